// Round 5
// baseline (234.544 us; speedup 1.0000x reference)
//
#include <hip/hip_runtime.h>
#include <hip/hip_fp16.h>

constexpr int B = 2, H = 12, S = 2048, D = 64;
constexpr int TQ = 16;            // query rows per block
constexpr int SPAD = 2056;        // f16 per score row (2048 + 8: rotates banks, keeps 16B align)
constexpr int NBLK_Q = S / TQ;    // 128
constexpr size_t BHSD = (size_t)B * H * S * D;   // 3,145,728

using f16x8 = _Float16 __attribute__((ext_vector_type(8)));
using f16x4 = _Float16 __attribute__((ext_vector_type(4)));
using f32x4 = float __attribute__((ext_vector_type(4)));

// XOR-swizzle on f16 element index within a 2048-row: spreads 64B-stride b128
// reads across bank groups. 8-element-granule-preserving (bits 3..5 ^= bits 6..8).
__device__ __forceinline__ int swz(int k) { return k ^ (((k >> 6) & 7) << 3); }

// ---------------- pre-pass: K fp32 -> f16 (same [bh][k][d] layout) ----------------
__global__ __launch_bounds__(256)
void cvt_k_kernel(const float* __restrict__ K, _Float16* __restrict__ Kh) {
    const size_t i = ((size_t)blockIdx.x * 256 + threadIdx.x) * 4;
    const float4 x = *reinterpret_cast<const float4*>(K + i);
    f16x4 y;
    y[0] = (_Float16)x.x; y[1] = (_Float16)x.y; y[2] = (_Float16)x.z; y[3] = (_Float16)x.w;
    *reinterpret_cast<f16x4*>(Kh + i) = y;
}

// ---------------- pre-pass: V fp32 [bh][k][d] -> f16 transposed [bh][d][k] -------
__global__ __launch_bounds__(256)
void tr_v_kernel(const float* __restrict__ V, _Float16* __restrict__ Vt) {
    __shared__ alignas(16) _Float16 tl[64][68];
    const int bh = blockIdx.x >> 5;
    const int k0 = (blockIdx.x & 31) * 64;
    const int tid = threadIdx.x;
    const int d4 = tid & 15, kl = tid >> 4;
    const float* Vb = V + (size_t)bh * S * D;
    #pragma unroll
    for (int i = 0; i < 4; ++i) {
        const int k = kl + 16 * i;
        const float4 x = *reinterpret_cast<const float4*>(Vb + (size_t)(k0 + k) * D + d4 * 4);
        f16x4 y;
        y[0] = (_Float16)x.x; y[1] = (_Float16)x.y; y[2] = (_Float16)x.z; y[3] = (_Float16)x.w;
        *reinterpret_cast<f16x4*>(&tl[k][d4 * 4]) = y;
    }
    __syncthreads();
    const int d = tid >> 2;
    _Float16* Vtb = Vt + (size_t)bh * D * S + (size_t)d * S + k0;
    #pragma unroll
    for (int i = 0; i < 2; ++i) {
        const int kloc = ((tid & 3) * 2 + i) * 8;
        f16x8 v;
        #pragma unroll
        for (int j = 0; j < 8; ++j) v[j] = tl[kloc + j][d];
        *reinterpret_cast<f16x8*>(Vtb + kloc) = v;
    }
}

// ---------------- main fused kernel: 1024 threads / 16 waves ----------------
template <bool PRE>
__global__ __launch_bounds__(1024, 8)
void sparsemax_attn_kernel(const float* __restrict__ Q, const float* __restrict__ K,
                           const float* __restrict__ V, const float* __restrict__ mask,
                           const float* __restrict__ scale, float* __restrict__ out,
                           const _Float16* __restrict__ Kh, const _Float16* __restrict__ Vt)
{
    __shared__ alignas(16) _Float16 s_sh[TQ * SPAD];   // 65792 B scores [q][k-swz]; reused f32 red
    __shared__ float tau_s[TQ];

    const int tid  = threadIdx.x;
    const int lane = tid & 63;
    const int w    = tid >> 6;              // wave 0..15
    const int row  = lane & 15;
    const int grp  = lane >> 4;             // 0..3
    const int bh   = blockIdx.x / NBLK_Q;
    const int qt   = blockIdx.x - bh * NBLK_Q;
    const int b    = bh / H;
    const int h    = bh - b * H;
    const int q0   = qt * TQ;

    const size_t bhSD = (size_t)bh * S * D;
    const float* mrow = mask + (size_t)b * S;
    const float  sc   = __expf(scale[h]) * 0.125f;

    // ---- Q fragments, sc folded in: qa[c][j] = Q[q0+row][c*32+grp*8+j] * sc ----
    f16x8 qa[2];
    {
        const float* qr = Q + bhSD + (size_t)(q0 + row) * D + grp * 8;
        #pragma unroll
        for (int c = 0; c < 2; ++c) {
            const float4 x0 = *reinterpret_cast<const float4*>(qr + c * 32);
            const float4 x1 = *reinterpret_cast<const float4*>(qr + c * 32 + 4);
            qa[c][0] = (_Float16)(x0.x * sc); qa[c][1] = (_Float16)(x0.y * sc);
            qa[c][2] = (_Float16)(x0.z * sc); qa[c][3] = (_Float16)(x0.w * sc);
            qa[c][4] = (_Float16)(x1.x * sc); qa[c][5] = (_Float16)(x1.y * sc);
            qa[c][6] = (_Float16)(x1.z * sc); qa[c][7] = (_Float16)(x1.w * sc);
        }
    }

    // ---------------- Phase 1: S^T tiles via mfma(K, Q) -> [q][k] LDS ----------------
    // D[key-in-tile = grp*4+r][q = row]; lane stores f16x4 (4 consecutive k) as one b64.
    for (int t = w * 8; t < w * 8 + 8; ++t) {
        const int key0 = t * 16;
        f16x8 kb0, kb1;
        if constexpr (PRE) {
            const _Float16* kp = Kh + bhSD + (size_t)(key0 + row) * D + grp * 8;
            kb0 = *reinterpret_cast<const f16x8*>(kp);
            kb1 = *reinterpret_cast<const f16x8*>(kp + 32);
        } else {
            const float* kp = K + bhSD + (size_t)(key0 + row) * D + grp * 8;
            #pragma unroll
            for (int c = 0; c < 2; ++c) {
                const float4 x0 = *reinterpret_cast<const float4*>(kp + c * 32);
                const float4 x1 = *reinterpret_cast<const float4*>(kp + c * 32 + 4);
                f16x8& kb = c ? kb1 : kb0;
                kb[0] = (_Float16)x0.x; kb[1] = (_Float16)x0.y;
                kb[2] = (_Float16)x0.z; kb[3] = (_Float16)x0.w;
                kb[4] = (_Float16)x1.x; kb[5] = (_Float16)x1.y;
                kb[6] = (_Float16)x1.z; kb[7] = (_Float16)x1.w;
            }
        }
        f32x4 acc = {0.f, 0.f, 0.f, 0.f};
        acc = __builtin_amdgcn_mfma_f32_16x16x32_f16(kb0, qa[0], acc, 0, 0, 0);
        acc = __builtin_amdgcn_mfma_f32_16x16x32_f16(kb1, qa[1], acc, 0, 0, 0);
        const float4 msk = *reinterpret_cast<const float4*>(mrow + key0 + grp * 4);
        f16x4 st;
        #pragma unroll
        for (int r = 0; r < 4; ++r) {
            const float madd = fmaf((&msk.x)[r], 1.0e9f, -1.0e9f);  // -(1-m)*1e9
            const float v = fminf(fmaxf(acc[r] + madd, -60000.0f), 60000.0f);
            st[r] = (_Float16)v;
        }
        *reinterpret_cast<f16x4*>(&s_sh[row * SPAD + swz(key0 + grp * 4)]) = st;
    }
    __syncthreads();

    // ---------------- Phase 2: tau for row q=w (wave-parallel, candidate-pruned) ------
    {
        const _Float16* zrow = &s_sh[w * SPAD];
        float z32[32];
        #pragma unroll
        for (int j = 0; j < 4; ++j) {
            const f16x8 zv = *reinterpret_cast<const f16x8*>(&zrow[swz(lane * 32 + j * 8)]);
            #pragma unroll
            for (int e = 0; e < 8; ++e) z32[j * 8 + e] = (float)zv[e];
        }
        float m = z32[0];
        #pragma unroll
        for (int j = 1; j < 32; ++j) m = fmaxf(m, z32[j]);
        #pragma unroll
        for (int off = 32; off >= 1; off >>= 1) m = fmaxf(m, __shfl_xor(m, off));
        const float thr = m - 1.0f;          // tau* >= max-1: only z > thr can be in support
        float c0 = -1.0e30f, c1 = -1.0e30f, c2 = -1.0e30f;
        int lc = 0;
        #pragma unroll
        for (int j = 0; j < 32; ++j) {
            const float zz = z32[j];
            if (zz > thr) {
                c2 = (lc == 2) ? zz : c2;
                c1 = (lc == 1) ? zz : c1;
                c0 = (lc == 0) ? zz : c0;
                ++lc;
            }
        }
        float tau = thr;
        if (__ballot(lc > 3) == 0ULL) {
            // fast path: <=3 candidates per lane (covers ~99.9% of rows)
            #pragma unroll 1
            for (int it = 0; it < 24; ++it) {
                const float d0 = c0 - tau, d1 = c1 - tau, d2 = c2 - tau;
                float s = fmaxf(d0, 0.f) + fmaxf(d1, 0.f) + fmaxf(d2, 0.f);
                float c = (d0 > 0.f ? 1.f : 0.f) + (d1 > 0.f ? 1.f : 0.f) + (d2 > 0.f ? 1.f : 0.f);
                #pragma unroll
                for (int off = 32; off >= 1; off >>= 1) {
                    s += __shfl_xor(s, off);
                    c += __shfl_xor(c, off);
                }
                const float tn = tau + (s - 1.0f) / c;
                if (!(tn > tau)) break;       // support stable -> exact
                tau = tn;
            }
        } else {
            // rare fallback (candidate overflow / fully-masked rows): full 32-elem Newton
            #pragma unroll 1
            for (int it = 0; it < 32; ++it) {
                float s = 0.f, c = 0.f;
                #pragma unroll
                for (int j = 0; j < 32; ++j) {
                    const float d = z32[j] - tau;
                    s += fmaxf(d, 0.f);
                    c += (d > 0.f ? 1.f : 0.f);
                }
                #pragma unroll
                for (int off = 32; off >= 1; off >>= 1) {
                    s += __shfl_xor(s, off);
                    c += __shfl_xor(c, off);
                }
                const float tn = tau + (s - 1.0f) / c;
                if (!(tn > tau)) break;
                tau = tn;
            }
        }
        if (lane == 0) tau_s[w] = tau;
    }
    __syncthreads();

    // ---------------- Phase 3: out = P.V (MFMA); P = max(z - tau, 0) in packed f16 ----
    const float tau_row = tau_s[row];
    f16x8 t8;
    {
        const _Float16 th = (_Float16)tau_row;
        #pragma unroll
        for (int e = 0; e < 8; ++e) t8[e] = th;
    }
    f32x4 o[4] = {{0.f,0.f,0.f,0.f},{0.f,0.f,0.f,0.f},{0.f,0.f,0.f,0.f},{0.f,0.f,0.f,0.f}};
    for (int c = w * 4; c < w * 4 + 4; ++c) {
        const int k0 = c * 32;
        const f16x8 zv = *reinterpret_cast<const f16x8*>(&s_sh[row * SPAD + swz(k0 + grp * 8)]);
        const f16x8 pa = __builtin_elementwise_max(zv - t8, (f16x8)(_Float16)0.0f);
        #pragma unroll
        for (int n = 0; n < 4; ++n) {
            f16x8 vb;
            if constexpr (PRE) {
                vb = *reinterpret_cast<const f16x8*>(
                    Vt + (size_t)bh * D * S + (size_t)(n * 16 + row) * S + k0 + grp * 8);
            } else {
                #pragma unroll
                for (int j = 0; j < 8; ++j)
                    vb[j] = (_Float16)V[bhSD + (size_t)(k0 + grp * 8 + j) * D + n * 16 + row];
            }
            o[n] = __builtin_amdgcn_mfma_f32_16x16x32_f16(pa, vb, o[n], 0, 0, 0);
        }
    }
    __syncthreads();   // scores fully consumed; reuse LDS for f32 reduction

    // cross-wave reduction: red[16 partials][16 q][64 d] f32 = 64 KB
    float* red = reinterpret_cast<float*>(s_sh);
    #pragma unroll
    for (int n = 0; n < 4; ++n)
        #pragma unroll
        for (int r = 0; r < 4; ++r)
            red[w * 1024 + (grp * 4 + r) * 64 + n * 16 + row] = o[n][r];
    __syncthreads();

    {
        const int q = tid >> 6;               // 0..15
        const int d = tid & 63;               // 0..63
        float sum = 0.f;
        #pragma unroll
        for (int p = 0; p < 16; ++p)
            sum += red[p * 1024 + q * 64 + d];
        out[bhSD + (size_t)(q0 + q) * D + d] = sum;
    }
}

extern "C" void kernel_launch(void* const* d_in, const int* in_sizes, int n_in,
                              void* d_out, int out_size, void* d_ws, size_t ws_size,
                              hipStream_t stream) {
    const float* Q     = (const float*)d_in[0];
    const float* K     = (const float*)d_in[1];
    const float* V     = (const float*)d_in[2];
    const float* mask  = (const float*)d_in[3];
    const float* scale = (const float*)d_in[4];
    float* out = (float*)d_out;

    const size_t need = 2 * BHSD * sizeof(_Float16);   // Kh + Vt = 12.6 MB
    if (ws_size >= need) {
        _Float16* Kh = (_Float16*)d_ws;
        _Float16* Vt = Kh + BHSD;
        cvt_k_kernel<<<dim3((unsigned)(BHSD / (256 * 4))), dim3(256), 0, stream>>>(K, Kh);
        tr_v_kernel<<<dim3(B * H * (S / 64)), dim3(256), 0, stream>>>(V, Vt);
        sparsemax_attn_kernel<true><<<dim3(B * H * NBLK_Q), dim3(1024), 0, stream>>>(
            Q, K, V, mask, scale, out, Kh, Vt);
    } else {
        sparsemax_attn_kernel<false><<<dim3(B * H * NBLK_Q), dim3(1024), 0, stream>>>(
            Q, K, V, mask, scale, out, nullptr, nullptr);
    }
}

// Round 6
// 192.161 us; speedup vs baseline: 1.2206x; 1.2206x over previous
//
#include <hip/hip_runtime.h>
#include <hip/hip_fp16.h>

constexpr int B = 2, H = 12, S = 2048, D = 64;
constexpr int TQ = 16;            // query rows per block
constexpr int NBLK_Q = S / TQ;    // 128
constexpr size_t BHSD = (size_t)B * H * S * D;   // 3,145,728

using f16x8 = _Float16 __attribute__((ext_vector_type(8)));
using f16x4 = _Float16 __attribute__((ext_vector_type(4)));
using f32x4 = float   __attribute__((ext_vector_type(4)));

// score swizzle: XOR element-index bits 3-5 with ((k>>6) ^ q). Spreads:
//  - phase1 store / phase3 read (rows vary per lane, k-window fixed): via q term
//  - phase2 read (row fixed, lane*32 element stride): via k>>6 term
__device__ __forceinline__ int swz2(int q, int k) {
    return k ^ ((((k >> 6) ^ q) & 7) << 3);
}

__device__ __forceinline__ void gl_lds16(const _Float16* g, _Float16* l) {
    __builtin_amdgcn_global_load_lds(
        (const __attribute__((address_space(1))) unsigned int*)g,
        (__attribute__((address_space(3))) unsigned int*)l, 16, 0, 0);
}

// ---- pre-pass: K fp32 [bh][key][d] -> f16 MFMA-tiled ----
// Kh[bh][tile t][c2][grp][row][e]  (elements: t*1024 + c2*512 + grp*128 + row*8 + e)
// where key = t*16 + row, d = c2*32 + grp*8 + e.
__global__ __launch_bounds__(256)
void cvt_k_kernel(const float* __restrict__ K, _Float16* __restrict__ Kh) {
    const int bh   = blockIdx.x >> 6;
    const int t    = (blockIdx.x & 63) * 2 + (threadIdx.x >> 7);
    const int f    = threadIdx.x & 127;           // c2*64 + grp*16 + row
    const int c2   = f >> 6, grp = (f >> 4) & 3, row = f & 15;
    const size_t bhSD = (size_t)bh * S * D;
    const float* src = K + bhSD + (size_t)(t * 16 + row) * D + c2 * 32 + grp * 8;
    const float4 x0 = *reinterpret_cast<const float4*>(src);
    const float4 x1 = *reinterpret_cast<const float4*>(src + 4);
    f16x8 y;
    y[0] = (_Float16)x0.x; y[1] = (_Float16)x0.y; y[2] = (_Float16)x0.z; y[3] = (_Float16)x0.w;
    y[4] = (_Float16)x1.x; y[5] = (_Float16)x1.y; y[6] = (_Float16)x1.z; y[7] = (_Float16)x1.w;
    *reinterpret_cast<f16x8*>(Kh + bhSD + (size_t)t * 1024 + f * 8) = y;
}

// ---- pre-pass: V fp32 [bh][k][d] -> f16 MFMA-tiled transposed ----
// Vt[bh][chunk c][dh][n2][grp][row][e] (elements: c*2048 + dh*1024 + n2*512 + grp*128 + row*8 + e)
// where d = dh*32 + n2*16 + row, k = c*32 + grp*8 + e.
__global__ __launch_bounds__(256)
void tr_v_kernel(const float* __restrict__ V, _Float16* __restrict__ Vt) {
    const int bh = blockIdx.x >> 6;
    const int c  = blockIdx.x & 63;
    const int f  = threadIdx.x;                   // dh*128 + n2*64 + grp*16 + row
    const int dh = f >> 7, n2 = (f >> 6) & 1, grp = (f >> 4) & 3, row = f & 15;
    const int d  = dh * 32 + n2 * 16 + row;
    const size_t bhSD = (size_t)bh * S * D;
    const float* src = V + bhSD + (size_t)(c * 32 + grp * 8) * D + d;
    f16x8 y;
    #pragma unroll
    for (int e = 0; e < 8; ++e) y[e] = (_Float16)src[e * D];
    *reinterpret_cast<f16x8*>(Vt + bhSD + (size_t)c * 2048 + f * 8) = y;
}

// ---------------- main fused kernel: 1024 threads / 16 waves ----------------
template <bool PRE>
__global__ __launch_bounds__(1024, 4)
void sparsemax_attn_kernel(const float* __restrict__ Q, const float* __restrict__ K,
                           const float* __restrict__ V, const float* __restrict__ mask,
                           const float* __restrict__ scale, float* __restrict__ out,
                           const _Float16* __restrict__ Kh, const _Float16* __restrict__ Vt)
{
    __shared__ alignas(16) _Float16 s_sh[TQ * 2048];      // 64 KB scores [q][k-swz]; f32 red later
    __shared__ alignas(16) float    madd_sh[S];           // 8 KB mask add terms
    __shared__ alignas(16) _Float16 stage_sh[16 * 2048];  // 64 KB: 4 KB per wave (2 x 2KB bufs)
    __shared__ float tau_s[TQ];

    const int tid  = threadIdx.x;
    const int lane = tid & 63;
    const int w    = tid >> 6;              // wave 0..15
    const int row  = lane & 15;
    const int grp  = lane >> 4;             // 0..3
    const int bh   = blockIdx.x / NBLK_Q;
    const int qt   = blockIdx.x - bh * NBLK_Q;
    const int b    = bh / H;
    const int h    = bh - b * H;
    const int q0   = qt * TQ;

    const size_t bhSD = (size_t)bh * S * D;
    const float* mrow = mask + (size_t)b * S;
    const float  sc   = __expf(scale[h]) * 0.125f;

    // mask -> LDS additive terms
    madd_sh[tid]        = (1.0f - mrow[tid])        * -1.0e9f;
    madd_sh[tid + 1024] = (1.0f - mrow[tid + 1024]) * -1.0e9f;

    // ---- Q fragments, sc folded in: qa[c][j] = Q[q0+row][c*32+grp*8+j] * sc ----
    f16x8 qa[2];
    {
        const float* qr = Q + bhSD + (size_t)(q0 + row) * D + grp * 8;
        #pragma unroll
        for (int c = 0; c < 2; ++c) {
            const float4 x0 = *reinterpret_cast<const float4*>(qr + c * 32);
            const float4 x1 = *reinterpret_cast<const float4*>(qr + c * 32 + 4);
            qa[c][0] = (_Float16)(x0.x * sc); qa[c][1] = (_Float16)(x0.y * sc);
            qa[c][2] = (_Float16)(x0.z * sc); qa[c][3] = (_Float16)(x0.w * sc);
            qa[c][4] = (_Float16)(x1.x * sc); qa[c][5] = (_Float16)(x1.y * sc);
            qa[c][6] = (_Float16)(x1.z * sc); qa[c][7] = (_Float16)(x1.w * sc);
        }
    }
    __syncthreads();   // madd ready; VMEM drained -> clean vmcnt accounting

    _Float16* stW = stage_sh + w * 2048;    // this wave's private 4 KB staging

    // ---------------- Phase 1: S^T tiles via mfma(K, Q) -> [q][k] LDS ----------------
    // wave w owns key-tiles w*8 .. w*8+7 (contiguous 16 KB stream in tiled Kh)
    if constexpr (PRE) {
        const _Float16* ksrc = Kh + bhSD + (size_t)(w * 8) * 1024;
        gl_lds16(ksrc + lane * 8, stW);                       // tile 0
        gl_lds16(ksrc + 512 + lane * 8, stW + 512);
        gl_lds16(ksrc + 1024 + lane * 8, stW + 1024);         // tile 1
        gl_lds16(ksrc + 1536 + lane * 8, stW + 1536);
        #pragma unroll
        for (int i = 0; i < 8; ++i) {
            if (i < 7) asm volatile("s_waitcnt vmcnt(2)" ::: "memory");
            else       asm volatile("s_waitcnt vmcnt(0)" ::: "memory");
            const _Float16* buf = stW + (i & 1) * 1024;
            const f16x8 kb0 = *reinterpret_cast<const f16x8*>(buf + grp * 128 + row * 8);
            const f16x8 kb1 = *reinterpret_cast<const f16x8*>(buf + 512 + grp * 128 + row * 8);
            if (i < 6) {      // prefetch tile i+2 into buf[i&1]'s sibling slot
                const _Float16* s2 = ksrc + (size_t)(i + 2) * 1024;
                _Float16* d2 = stW + (i & 1) * 1024;   // buffer just consumed by the reads above
                gl_lds16(s2 + lane * 8, d2);
                gl_lds16(s2 + 512 + lane * 8, d2 + 512);
            }
            const int key0 = (w * 8 + i) * 16;
            f32x4 acc = {0.f, 0.f, 0.f, 0.f};
            acc = __builtin_amdgcn_mfma_f32_16x16x32_f16(kb0, qa[0], acc, 0, 0, 0);
            acc = __builtin_amdgcn_mfma_f32_16x16x32_f16(kb1, qa[1], acc, 0, 0, 0);
            const float4 ma = *reinterpret_cast<const float4*>(madd_sh + key0 + grp * 4);
            f16x4 st;
            #pragma unroll
            for (int r = 0; r < 4; ++r) {
                const float v = fminf(fmaxf(acc[r] + (&ma.x)[r], -60000.0f), 60000.0f);
                st[r] = (_Float16)v;
            }
            *reinterpret_cast<f16x4*>(&s_sh[row * 2048 + swz2(row, key0 + grp * 4)]) = st;
        }
    } else {
        for (int t = w * 8; t < w * 8 + 8; ++t) {
            const int key0 = t * 16;
            const float* kp = K + bhSD + (size_t)(key0 + row) * D + grp * 8;
            f16x8 kb0, kb1;
            #pragma unroll
            for (int c = 0; c < 2; ++c) {
                const float4 x0 = *reinterpret_cast<const float4*>(kp + c * 32);
                const float4 x1 = *reinterpret_cast<const float4*>(kp + c * 32 + 4);
                f16x8& kb = c ? kb1 : kb0;
                kb[0] = (_Float16)x0.x; kb[1] = (_Float16)x0.y;
                kb[2] = (_Float16)x0.z; kb[3] = (_Float16)x0.w;
                kb[4] = (_Float16)x1.x; kb[5] = (_Float16)x1.y;
                kb[6] = (_Float16)x1.z; kb[7] = (_Float16)x1.w;
            }
            f32x4 acc = {0.f, 0.f, 0.f, 0.f};
            acc = __builtin_amdgcn_mfma_f32_16x16x32_f16(kb0, qa[0], acc, 0, 0, 0);
            acc = __builtin_amdgcn_mfma_f32_16x16x32_f16(kb1, qa[1], acc, 0, 0, 0);
            const float4 ma = *reinterpret_cast<const float4*>(madd_sh + key0 + grp * 4);
            f16x4 st;
            #pragma unroll
            for (int r = 0; r < 4; ++r) {
                const float v = fminf(fmaxf(acc[r] + (&ma.x)[r], -60000.0f), 60000.0f);
                st[r] = (_Float16)v;
            }
            *reinterpret_cast<f16x4*>(&s_sh[row * 2048 + swz2(row, key0 + grp * 4)]) = st;
        }
    }
    __syncthreads();

    // ---------------- Phase 2: tau for row q=w (wave-parallel, candidate-pruned) ------
    {
        const _Float16* zrow = &s_sh[w * 2048];
        float z32[32];
        #pragma unroll
        for (int j = 0; j < 4; ++j) {
            const f16x8 zv = *reinterpret_cast<const f16x8*>(&zrow[swz2(w, lane * 32 + j * 8)]);
            #pragma unroll
            for (int e = 0; e < 8; ++e) z32[j * 8 + e] = (float)zv[e];
        }
        float m = z32[0];
        #pragma unroll
        for (int j = 1; j < 32; ++j) m = fmaxf(m, z32[j]);
        #pragma unroll
        for (int off = 32; off >= 1; off >>= 1) m = fmaxf(m, __shfl_xor(m, off));
        const float thr = m - 1.0f;          // tau* >= max-1
        float c0 = -1.0e30f, c1 = -1.0e30f, c2 = -1.0e30f;
        int lc = 0;
        #pragma unroll
        for (int j = 0; j < 32; ++j) {
            const float zz = z32[j];
            if (zz > thr) {
                c2 = (lc == 2) ? zz : c2;
                c1 = (lc == 1) ? zz : c1;
                c0 = (lc == 0) ? zz : c0;
                ++lc;
            }
        }
        float tau = thr;
        if (__ballot(lc > 3) == 0ULL) {
            #pragma unroll 1
            for (int it = 0; it < 24; ++it) {
                const float d0 = c0 - tau, d1 = c1 - tau, d2 = c2 - tau;
                float s = fmaxf(d0, 0.f) + fmaxf(d1, 0.f) + fmaxf(d2, 0.f);
                float c = (d0 > 0.f ? 1.f : 0.f) + (d1 > 0.f ? 1.f : 0.f) + (d2 > 0.f ? 1.f : 0.f);
                #pragma unroll
                for (int off = 32; off >= 1; off >>= 1) {
                    s += __shfl_xor(s, off);
                    c += __shfl_xor(c, off);
                }
                const float tn = tau + (s - 1.0f) / c;
                if (!(tn > tau)) break;       // support stable -> exact
                tau = tn;
            }
        } else {
            #pragma unroll 1
            for (int it = 0; it < 32; ++it) {
                float s = 0.f, c = 0.f;
                #pragma unroll
                for (int j = 0; j < 32; ++j) {
                    const float d = z32[j] - tau;
                    s += fmaxf(d, 0.f);
                    c += (d > 0.f ? 1.f : 0.f);
                }
                #pragma unroll
                for (int off = 32; off >= 1; off >>= 1) {
                    s += __shfl_xor(s, off);
                    c += __shfl_xor(c, off);
                }
                const float tn = tau + (s - 1.0f) / c;
                if (!(tn > tau)) break;
                tau = tn;
            }
        }
        if (lane == 0) tau_s[w] = tau;
    }
    __syncthreads();

    // ---------------- Phase 3: out = P.V (MFMA); P = max(z - tau, 0) packed f16 --------
    const float tau_row = tau_s[row];
    f16x8 t8;
    {
        const _Float16 th = (_Float16)tau_row;
        #pragma unroll
        for (int e = 0; e < 8; ++e) t8[e] = th;
    }
    f32x4 o[4] = {{0.f,0.f,0.f,0.f},{0.f,0.f,0.f,0.f},{0.f,0.f,0.f,0.f},{0.f,0.f,0.f,0.f}};
    if constexpr (PRE) {
        // wave w covers k in [w*128, w*128+128): 8 half-chunks of (32 d x 32 k) = 2 KB each
        const _Float16* vsrc = Vt + bhSD + (size_t)w * 8192;
        gl_lds16(vsrc + lane * 8, stW);                       // hc 0
        gl_lds16(vsrc + 512 + lane * 8, stW + 512);
        gl_lds16(vsrc + 1024 + lane * 8, stW + 1024);         // hc 1
        gl_lds16(vsrc + 1536 + lane * 8, stW + 1536);
        f16x8 pa;
        #pragma unroll
        for (int hc = 0; hc < 8; ++hc) {
            if (hc < 7) asm volatile("s_waitcnt vmcnt(2)" ::: "memory");
            else        asm volatile("s_waitcnt vmcnt(0)" ::: "memory");
            const _Float16* buf = stW + (hc & 1) * 1024;
            const f16x8 vb0 = *reinterpret_cast<const f16x8*>(buf + grp * 128 + row * 8);
            const f16x8 vb1 = *reinterpret_cast<const f16x8*>(buf + 512 + grp * 128 + row * 8);
            if (hc < 6) {
                const _Float16* s2 = vsrc + (size_t)(hc + 2) * 1024;
                _Float16* d2 = stW + (hc & 1) * 1024;
                gl_lds16(s2 + lane * 8, d2);
                gl_lds16(s2 + 512 + lane * 8, d2 + 512);
            }
            if ((hc & 1) == 0) {
                const int k0 = (w * 4 + (hc >> 1)) * 32;
                const f16x8 zv = *reinterpret_cast<const f16x8*>(
                    &s_sh[row * 2048 + swz2(row, k0 + grp * 8)]);
                pa = __builtin_elementwise_max(zv - t8, (f16x8)(_Float16)0.0f);
            }
            const int nb = (hc & 1) * 2;
            o[nb]     = __builtin_amdgcn_mfma_f32_16x16x32_f16(pa, vb0, o[nb],     0, 0, 0);
            o[nb + 1] = __builtin_amdgcn_mfma_f32_16x16x32_f16(pa, vb1, o[nb + 1], 0, 0, 0);
        }
    } else {
        for (int c = w * 4; c < w * 4 + 4; ++c) {
            const int k0 = c * 32;
            const f16x8 zv = *reinterpret_cast<const f16x8*>(
                &s_sh[row * 2048 + swz2(row, k0 + grp * 8)]);
            const f16x8 pa2 = __builtin_elementwise_max(zv - t8, (f16x8)(_Float16)0.0f);
            #pragma unroll
            for (int n = 0; n < 4; ++n) {
                f16x8 vb;
                #pragma unroll
                for (int j = 0; j < 8; ++j)
                    vb[j] = (_Float16)V[bhSD + (size_t)(k0 + grp * 8 + j) * D + n * 16 + row];
                o[n] = __builtin_amdgcn_mfma_f32_16x16x32_f16(pa2, vb, o[n], 0, 0, 0);
            }
        }
    }
    __syncthreads();   // scores fully consumed; reuse LDS for f32 reduction

    // cross-wave reduction: red[16 partials][16 q][64 d] f32 = 64 KB
    float* red = reinterpret_cast<float*>(s_sh);
    #pragma unroll
    for (int n = 0; n < 4; ++n)
        #pragma unroll
        for (int r = 0; r < 4; ++r)
            red[w * 1024 + (grp * 4 + r) * 64 + n * 16 + row] = o[n][r];
    __syncthreads();

    {
        const int q = tid >> 6;               // 0..15
        const int d = tid & 63;               // 0..63
        float sum = 0.f;
        #pragma unroll
        for (int p = 0; p < 16; ++p)
            sum += red[p * 1024 + q * 64 + d];
        out[bhSD + (size_t)(q0 + q) * D + d] = sum;
    }
}

extern "C" void kernel_launch(void* const* d_in, const int* in_sizes, int n_in,
                              void* d_out, int out_size, void* d_ws, size_t ws_size,
                              hipStream_t stream) {
    const float* Q     = (const float*)d_in[0];
    const float* K     = (const float*)d_in[1];
    const float* V     = (const float*)d_in[2];
    const float* mask  = (const float*)d_in[3];
    const float* scale = (const float*)d_in[4];
    float* out = (float*)d_out;

    const size_t need = 2 * BHSD * sizeof(_Float16);   // Kh + Vt = 12.6 MB
    if (ws_size >= need) {
        _Float16* Kh = (_Float16*)d_ws;
        _Float16* Vt = Kh + BHSD;
        cvt_k_kernel<<<dim3(B * H * 64), dim3(256), 0, stream>>>(K, Kh);
        tr_v_kernel<<<dim3(B * H * 64), dim3(256), 0, stream>>>(V, Vt);
        sparsemax_attn_kernel<true><<<dim3(B * H * NBLK_Q), dim3(1024), 0, stream>>>(
            Q, K, V, mask, scale, out, Kh, Vt);
    } else {
        sparsemax_attn_kernel<false><<<dim3(B * H * NBLK_Q), dim3(1024), 0, stream>>>(
            Q, K, V, mask, scale, out, nullptr, nullptr);
    }
}

// Round 7
// 145.673 us; speedup vs baseline: 1.6101x; 1.3191x over previous
//
#include <hip/hip_runtime.h>
#include <hip/hip_fp16.h>

constexpr int B = 2, H = 12, S = 2048, D = 64;
constexpr int TQ = 16;            // query rows per block
constexpr int NBLK_Q = S / TQ;    // 128
constexpr size_t BHSD = (size_t)B * H * S * D;   // 3,145,728

using f16x8 = _Float16 __attribute__((ext_vector_type(8)));
using f16x4 = _Float16 __attribute__((ext_vector_type(4)));
using f32x4 = float   __attribute__((ext_vector_type(4)));

// score swizzle: XOR element-index bits 3-5 with ((k>>6) ^ q).
__device__ __forceinline__ int swz2(int q, int k) {
    return k ^ ((((k >> 6) ^ q) & 7) << 3);
}

// ---- pre-pass: K fp32 [bh][key][d] -> f16 MFMA-tiled ----
// Kh element index: t*1024 + c2*512 + (grp*16+row)*8 + e ; key=t*16+row, d=c2*32+grp*8+e
__global__ __launch_bounds__(256)
void cvt_k_kernel(const float* __restrict__ K, _Float16* __restrict__ Kh) {
    const int bh   = blockIdx.x >> 6;
    const int t    = (blockIdx.x & 63) * 2 + (threadIdx.x >> 7);
    const int f    = threadIdx.x & 127;           // c2*64 + grp*16 + row
    const int c2   = f >> 6, grp = (f >> 4) & 3, row = f & 15;
    const size_t bhSD = (size_t)bh * S * D;
    const float* src = K + bhSD + (size_t)(t * 16 + row) * D + c2 * 32 + grp * 8;
    const float4 x0 = *reinterpret_cast<const float4*>(src);
    const float4 x1 = *reinterpret_cast<const float4*>(src + 4);
    f16x8 y;
    y[0] = (_Float16)x0.x; y[1] = (_Float16)x0.y; y[2] = (_Float16)x0.z; y[3] = (_Float16)x0.w;
    y[4] = (_Float16)x1.x; y[5] = (_Float16)x1.y; y[6] = (_Float16)x1.z; y[7] = (_Float16)x1.w;
    *reinterpret_cast<f16x8*>(Kh + bhSD + (size_t)t * 1024 + f * 8) = y;
}

// ---- pre-pass: V fp32 [bh][k][d] -> f16 MFMA-tiled transposed ----
// Vt element index: c*2048 + dh*1024 + n2*512 + (grp*16+row)*8 + e ; d=dh*32+n2*16+row, k=c*32+grp*8+e
__global__ __launch_bounds__(256)
void tr_v_kernel(const float* __restrict__ V, _Float16* __restrict__ Vt) {
    const int bh = blockIdx.x >> 6;
    const int c  = blockIdx.x & 63;
    const int f  = threadIdx.x;                   // dh*128 + n2*64 + grp*16 + row
    const int dh = f >> 7, n2 = (f >> 6) & 1, grp = (f >> 4) & 3, row = f & 15;
    const int d  = dh * 32 + n2 * 16 + row;
    const size_t bhSD = (size_t)bh * S * D;
    const float* src = V + bhSD + (size_t)(c * 32 + grp * 8) * D + d;
    f16x8 y;
    #pragma unroll
    for (int e = 0; e < 8; ++e) y[e] = (_Float16)src[e * D];
    *reinterpret_cast<f16x8*>(Vt + bhSD + (size_t)c * 2048 + f * 8) = y;
}

// ---------------- main fused kernel: 1024 threads / 16 waves, 2 blocks/CU ----------------
template <bool PRE>
__global__ __launch_bounds__(1024, 8)
void sparsemax_attn_kernel(const float* __restrict__ Q, const float* __restrict__ K,
                           const float* __restrict__ V, const float* __restrict__ mask,
                           const float* __restrict__ scale, float* __restrict__ out,
                           const _Float16* __restrict__ Kh, const _Float16* __restrict__ Vt)
{
    __shared__ alignas(16) _Float16 s_sh[TQ * 2048];      // 64 KB scores [q][k-swz]; f32 red later
    __shared__ alignas(16) float    madd_sh[S];           // 8 KB mask additive terms
    __shared__ float tau_s[TQ];

    const int tid  = threadIdx.x;
    const int lane = tid & 63;
    const int w    = tid >> 6;              // wave 0..15
    const int row  = lane & 15;
    const int grp  = lane >> 4;             // 0..3
    const int bh   = blockIdx.x / NBLK_Q;
    const int qt   = blockIdx.x - bh * NBLK_Q;
    const int b    = bh / H;
    const int h    = bh - b * H;
    const int q0   = qt * TQ;

    const size_t bhSD = (size_t)bh * S * D;
    const float* mrow = mask + (size_t)b * S;
    const float  sc   = __expf(scale[h]) * 0.125f;

    // mask -> LDS additive terms
    madd_sh[tid]        = (1.0f - mrow[tid])        * -1.0e9f;
    madd_sh[tid + 1024] = (1.0f - mrow[tid + 1024]) * -1.0e9f;

    // ---- Q fragments, sc folded in: qa[c][j] = Q[q0+row][c*32+grp*8+j] * sc ----
    f16x8 qa[2];
    {
        const float* qr = Q + bhSD + (size_t)(q0 + row) * D + grp * 8;
        #pragma unroll
        for (int c = 0; c < 2; ++c) {
            const float4 x0 = *reinterpret_cast<const float4*>(qr + c * 32);
            const float4 x1 = *reinterpret_cast<const float4*>(qr + c * 32 + 4);
            qa[c][0] = (_Float16)(x0.x * sc); qa[c][1] = (_Float16)(x0.y * sc);
            qa[c][2] = (_Float16)(x0.z * sc); qa[c][3] = (_Float16)(x0.w * sc);
            qa[c][4] = (_Float16)(x1.x * sc); qa[c][5] = (_Float16)(x1.y * sc);
            qa[c][6] = (_Float16)(x1.z * sc); qa[c][7] = (_Float16)(x1.w * sc);
        }
    }
    __syncthreads();   // madd ready

    // ---------------- Phase 1: S^T tiles via mfma(K, Q) -> [q][k] LDS ----------------
    // wave w owns key-tiles w*8 .. w*8+7; fragment = bytes lane*16 of each 1 KB tile (coalesced)
    if constexpr (PRE) {
        const _Float16* ksrc = Kh + bhSD + (size_t)(w * 8) * 1024 + lane * 8;
        f16x8 ka0 = *reinterpret_cast<const f16x8*>(ksrc);
        f16x8 ka1 = *reinterpret_cast<const f16x8*>(ksrc + 512);
        #pragma unroll
        for (int i = 0; i < 8; ++i) {
            f16x8 nb0, nb1;
            if (i < 7) {
                nb0 = *reinterpret_cast<const f16x8*>(ksrc + (i + 1) * 1024);
                nb1 = *reinterpret_cast<const f16x8*>(ksrc + (i + 1) * 1024 + 512);
            }
            f32x4 acc = {0.f, 0.f, 0.f, 0.f};
            acc = __builtin_amdgcn_mfma_f32_16x16x32_f16(ka0, qa[0], acc, 0, 0, 0);
            acc = __builtin_amdgcn_mfma_f32_16x16x32_f16(ka1, qa[1], acc, 0, 0, 0);
            const int key0 = (w * 8 + i) * 16;
            const float4 ma = *reinterpret_cast<const float4*>(madd_sh + key0 + grp * 4);
            f16x4 st;
            #pragma unroll
            for (int r = 0; r < 4; ++r) {
                const float v = fminf(fmaxf(acc[r] + (&ma.x)[r], -60000.0f), 60000.0f);
                st[r] = (_Float16)v;
            }
            *reinterpret_cast<f16x4*>(&s_sh[row * 2048 + swz2(row, key0 + grp * 4)]) = st;
            ka0 = nb0; ka1 = nb1;
        }
    } else {
        for (int t = w * 8; t < w * 8 + 8; ++t) {
            const int key0 = t * 16;
            const float* kp = K + bhSD + (size_t)(key0 + row) * D + grp * 8;
            f16x8 kb0, kb1;
            #pragma unroll
            for (int c = 0; c < 2; ++c) {
                const float4 x0 = *reinterpret_cast<const float4*>(kp + c * 32);
                const float4 x1 = *reinterpret_cast<const float4*>(kp + c * 32 + 4);
                f16x8& kb = c ? kb1 : kb0;
                kb[0] = (_Float16)x0.x; kb[1] = (_Float16)x0.y;
                kb[2] = (_Float16)x0.z; kb[3] = (_Float16)x0.w;
                kb[4] = (_Float16)x1.x; kb[5] = (_Float16)x1.y;
                kb[6] = (_Float16)x1.z; kb[7] = (_Float16)x1.w;
            }
            f32x4 acc = {0.f, 0.f, 0.f, 0.f};
            acc = __builtin_amdgcn_mfma_f32_16x16x32_f16(kb0, qa[0], acc, 0, 0, 0);
            acc = __builtin_amdgcn_mfma_f32_16x16x32_f16(kb1, qa[1], acc, 0, 0, 0);
            const float4 ma = *reinterpret_cast<const float4*>(madd_sh + key0 + grp * 4);
            f16x4 st;
            #pragma unroll
            for (int r = 0; r < 4; ++r) {
                const float v = fminf(fmaxf(acc[r] + (&ma.x)[r], -60000.0f), 60000.0f);
                st[r] = (_Float16)v;
            }
            *reinterpret_cast<f16x4*>(&s_sh[row * 2048 + swz2(row, key0 + grp * 4)]) = st;
        }
    }
    __syncthreads();

    // ---------------- Phase 2: tau for row q=w (wave-parallel, candidate-pruned) ------
    {
        const _Float16* zrow = &s_sh[w * 2048];
        float z32[32];
        #pragma unroll
        for (int j = 0; j < 4; ++j) {
            const f16x8 zv = *reinterpret_cast<const f16x8*>(&zrow[swz2(w, lane * 32 + j * 8)]);
            #pragma unroll
            for (int e = 0; e < 8; ++e) z32[j * 8 + e] = (float)zv[e];
        }
        float m = z32[0];
        #pragma unroll
        for (int j = 1; j < 32; ++j) m = fmaxf(m, z32[j]);
        #pragma unroll
        for (int off = 32; off >= 1; off >>= 1) m = fmaxf(m, __shfl_xor(m, off));
        const float thr = m - 1.0f;          // tau* >= max-1
        float c0 = -1.0e30f, c1 = -1.0e30f, c2 = -1.0e30f;
        int lc = 0;
        #pragma unroll
        for (int j = 0; j < 32; ++j) {
            const float zz = z32[j];
            if (zz > thr) {
                c2 = (lc == 2) ? zz : c2;
                c1 = (lc == 1) ? zz : c1;
                c0 = (lc == 0) ? zz : c0;
                ++lc;
            }
        }
        float tau = thr;
        if (__ballot(lc > 3) == 0ULL) {
            #pragma unroll 1
            for (int it = 0; it < 24; ++it) {
                const float d0 = c0 - tau, d1 = c1 - tau, d2 = c2 - tau;
                float s = fmaxf(d0, 0.f) + fmaxf(d1, 0.f) + fmaxf(d2, 0.f);
                float c = (d0 > 0.f ? 1.f : 0.f) + (d1 > 0.f ? 1.f : 0.f) + (d2 > 0.f ? 1.f : 0.f);
                #pragma unroll
                for (int off = 32; off >= 1; off >>= 1) {
                    s += __shfl_xor(s, off);
                    c += __shfl_xor(c, off);
                }
                const float tn = tau + (s - 1.0f) / c;
                if (!(tn > tau)) break;       // support stable -> exact
                tau = tn;
            }
        } else {
            #pragma unroll 1
            for (int it = 0; it < 32; ++it) {
                float s = 0.f, c = 0.f;
                #pragma unroll
                for (int j = 0; j < 32; ++j) {
                    const float d = z32[j] - tau;
                    s += fmaxf(d, 0.f);
                    c += (d > 0.f ? 1.f : 0.f);
                }
                #pragma unroll
                for (int off = 32; off >= 1; off >>= 1) {
                    s += __shfl_xor(s, off);
                    c += __shfl_xor(c, off);
                }
                const float tn = tau + (s - 1.0f) / c;
                if (!(tn > tau)) break;
                tau = tn;
            }
        }
        if (lane == 0) tau_s[w] = tau;
    }
    __syncthreads();

    // ---------------- Phase 3: out = P.V (MFMA); P = max(z - tau, 0) packed f16 --------
    const float tau_row = tau_s[row];
    f16x8 t8;
    {
        const _Float16 th = (_Float16)tau_row;
        #pragma unroll
        for (int e = 0; e < 8; ++e) t8[e] = th;
    }
    f32x4 o[4] = {{0.f,0.f,0.f,0.f},{0.f,0.f,0.f,0.f},{0.f,0.f,0.f,0.f},{0.f,0.f,0.f,0.f}};
    if constexpr (PRE) {
        // wave w covers k in [w*128, w*128+128): 4 chunks of 32 k; per chunk 4 n-tiles
        const _Float16* vsrc = Vt + bhSD + (size_t)w * 8192 + lane * 8;
        f16x8 va0 = *reinterpret_cast<const f16x8*>(vsrc);
        f16x8 va1 = *reinterpret_cast<const f16x8*>(vsrc + 512);
        #pragma unroll
        for (int hc = 0; hc < 8; ++hc) {
            f16x8 nb0, nb1;
            if (hc < 7) {
                nb0 = *reinterpret_cast<const f16x8*>(vsrc + (hc + 1) * 1024);
                nb1 = *reinterpret_cast<const f16x8*>(vsrc + (hc + 1) * 1024 + 512);
            }
            f16x8 pa;
            if ((hc & 1) == 0) {
                const int k0 = (w * 4 + (hc >> 1)) * 32;
                const f16x8 zv = *reinterpret_cast<const f16x8*>(
                    &s_sh[row * 2048 + swz2(row, k0 + grp * 8)]);
                pa = __builtin_elementwise_max(zv - t8, (f16x8)(_Float16)0.0f);
            } else {
                const int k0 = (w * 4 + (hc >> 1)) * 32;
                const f16x8 zv = *reinterpret_cast<const f16x8*>(
                    &s_sh[row * 2048 + swz2(row, k0 + grp * 8)]);
                pa = __builtin_elementwise_max(zv - t8, (f16x8)(_Float16)0.0f);
            }
            const int nb = (hc & 1) * 2;
            o[nb]     = __builtin_amdgcn_mfma_f32_16x16x32_f16(pa, va0, o[nb],     0, 0, 0);
            o[nb + 1] = __builtin_amdgcn_mfma_f32_16x16x32_f16(pa, va1, o[nb + 1], 0, 0, 0);
            va0 = nb0; va1 = nb1;
        }
    } else {
        for (int c = w * 4; c < w * 4 + 4; ++c) {
            const int k0 = c * 32;
            const f16x8 zv = *reinterpret_cast<const f16x8*>(
                &s_sh[row * 2048 + swz2(row, k0 + grp * 8)]);
            const f16x8 pa2 = __builtin_elementwise_max(zv - t8, (f16x8)(_Float16)0.0f);
            #pragma unroll
            for (int n = 0; n < 4; ++n) {
                f16x8 vb;
                #pragma unroll
                for (int j = 0; j < 8; ++j)
                    vb[j] = (_Float16)V[bhSD + (size_t)(k0 + grp * 8 + j) * D + n * 16 + row];
                o[n] = __builtin_amdgcn_mfma_f32_16x16x32_f16(pa2, vb, o[n], 0, 0, 0);
            }
        }
    }
    __syncthreads();   // scores fully consumed; reuse LDS for f32 reduction

    // cross-wave reduction: red[16 partials][16 q][64 d] f32 = 64 KB
    float* red = reinterpret_cast<float*>(s_sh);
    #pragma unroll
    for (int n = 0; n < 4; ++n)
        #pragma unroll
        for (int r = 0; r < 4; ++r)
            red[w * 1024 + (grp * 4 + r) * 64 + n * 16 + row] = o[n][r];
    __syncthreads();

    {
        const int q = tid >> 6;               // 0..15
        const int d = tid & 63;               // 0..63
        float sum = 0.f;
        #pragma unroll
        for (int p = 0; p < 16; ++p)
            sum += red[p * 1024 + q * 64 + d];
        out[bhSD + (size_t)(q0 + q) * D + d] = sum;
    }
}

extern "C" void kernel_launch(void* const* d_in, const int* in_sizes, int n_in,
                              void* d_out, int out_size, void* d_ws, size_t ws_size,
                              hipStream_t stream) {
    const float* Q     = (const float*)d_in[0];
    const float* K     = (const float*)d_in[1];
    const float* V     = (const float*)d_in[2];
    const float* mask  = (const float*)d_in[3];
    const float* scale = (const float*)d_in[4];
    float* out = (float*)d_out;

    const size_t need = 2 * BHSD * sizeof(_Float16);   // Kh + Vt = 12.6 MB
    if (ws_size >= need) {
        _Float16* Kh = (_Float16*)d_ws;
        _Float16* Vt = Kh + BHSD;
        cvt_k_kernel<<<dim3(B * H * 64), dim3(256), 0, stream>>>(K, Kh);
        tr_v_kernel<<<dim3(B * H * 64), dim3(256), 0, stream>>>(V, Vt);
        sparsemax_attn_kernel<true><<<dim3(B * H * NBLK_Q), dim3(1024), 0, stream>>>(
            Q, K, V, mask, scale, out, Kh, Vt);
    } else {
        sparsemax_attn_kernel<false><<<dim3(B * H * NBLK_Q), dim3(1024), 0, stream>>>(
            Q, K, V, mask, scale, out, nullptr, nullptr);
    }
}